// Round 6
// baseline (94.347 us; speedup 1.0000x reference)
//
#include <hip/hip_runtime.h>
#include <hip/hip_bf16.h>

#define D_FEAT_K 256

typedef float floatx4 __attribute__((ext_vector_type(4)));

// --- fully fused, single dispatch — one WAVE per graph, 4 waves/block ----
// result[g,c] = (sum_i o_i,c*e_i + b_c*S) / (S + 1e-16), e_i = exp(l_i)
// (global-max subtraction cancels algebraically; eps-term shift ~1e-14)
//
// Each wave computes its own exclusive offset by summing sizes[0..g) with
// int4 loads (40 KB array -> L1/L2-resident; overlapped with other waves'
// HBM streaming). Then: 16 lanes per row, 4 rows per wave iteration,
// row loop unrolled x2 (8 independent float4 loads in flight per lane
// before any cross-lane dependency). Only the gate logit is reduced per
// row; o-projection partials accumulate per-lane, reduced once per graph.
__global__ __launch_bounds__(256)
void fused_kernel(const float* __restrict__ states,
                  const int* __restrict__ sizes,
                  const float* __restrict__ gate_w,
                  const float* __restrict__ gate_b,
                  const float* __restrict__ out_w,
                  const float* __restrict__ out_b,
                  float2* __restrict__ outp,
                  int n_graphs) {
    const int wid  = threadIdx.x >> 6;
    const int lane = threadIdx.x & 63;
    const int g = blockIdx.x * 4 + wid;
    if (g >= n_graphs) return;          // whole-wave exit; no block syncs used

    // --- self-scan: off = sum(sizes[0..g)), redundantly per wave ---------
    int acc = 0;
    {
        const int nv = g >> 2;          // number of full int4 groups
        const int4* s4 = reinterpret_cast<const int4*>(sizes);
        for (int j = lane; j < nv; j += 64) {
            int4 v = s4[j];
            acc += v.x + v.y + v.z + v.w;
        }
        for (int j = (nv << 2) + lane; j < g; j += 64) acc += sizes[j];
#pragma unroll
        for (int m = 32; m >= 1; m >>= 1) acc += __shfl_xor(acc, m);
    }
    const int off = acc;
    const int sz  = sizes[g];

    const int q   = lane & 15;          // lane within row
    const int grp = lane >> 4;          // which of 4 rows per quad

    // per-lane weight slices: features f = 4q + 64k + j, k=0..3, j=0..3
    float4 gw[4], owA[4], owB[4];
#pragma unroll
    for (int k = 0; k < 4; ++k) {
        const int f0 = 4 * q + 64 * k;
        gw[k]  = *reinterpret_cast<const float4*>(gate_w + f0);
        // out_w is [256][2] row-major: (f,c) at 2f+c
        owA[k] = *reinterpret_cast<const float4*>(out_w + 2 * f0);       // c0(f),c1(f),c0(f+1),c1(f+1)
        owB[k] = *reinterpret_cast<const float4*>(out_w + 2 * f0 + 4);   // c0(f+2),c1(f+2),c0(f+3),c1(f+3)
    }
    const float gb = gate_b[0];

    float se = 0.f, s0 = 0.f, s1 = 0.f;   // per-lane accumulators

    int r = grp;
    // main loop: two row-quads (8 rows) per iteration, 8 loads in flight
    for (; r + 4 < sz; r += 8) {
        const float* rowA = states + (size_t)(off + r)     * D_FEAT_K;
        const float* rowB = states + (size_t)(off + r + 4) * D_FEAT_K;
        float plA = 0.f, p0A = 0.f, p1A = 0.f;
        float plB = 0.f, p0B = 0.f, p1B = 0.f;
        floatx4 sA[4], sB[4];
#pragma unroll
        for (int k = 0; k < 4; ++k)
            sA[k] = __builtin_nontemporal_load(
                reinterpret_cast<const floatx4*>(rowA + 4 * q + 64 * k));
#pragma unroll
        for (int k = 0; k < 4; ++k)
            sB[k] = __builtin_nontemporal_load(
                reinterpret_cast<const floatx4*>(rowB + 4 * q + 64 * k));
#pragma unroll
        for (int k = 0; k < 4; ++k) {
            plA += sA[k].x * gw[k].x  + sA[k].y * gw[k].y  + sA[k].z * gw[k].z  + sA[k].w * gw[k].w;
            p0A += sA[k].x * owA[k].x + sA[k].y * owA[k].z + sA[k].z * owB[k].x + sA[k].w * owB[k].z;
            p1A += sA[k].x * owA[k].y + sA[k].y * owA[k].w + sA[k].z * owB[k].y + sA[k].w * owB[k].w;
            plB += sB[k].x * gw[k].x  + sB[k].y * gw[k].y  + sB[k].z * gw[k].z  + sB[k].w * gw[k].w;
            p0B += sB[k].x * owA[k].x + sB[k].y * owA[k].z + sB[k].z * owB[k].x + sB[k].w * owB[k].z;
            p1B += sB[k].x * owA[k].y + sB[k].y * owA[k].w + sB[k].z * owB[k].y + sB[k].w * owB[k].w;
        }
#pragma unroll
        for (int m = 8; m >= 1; m >>= 1) {
            plA += __shfl_xor(plA, m);
            plB += __shfl_xor(plB, m);
        }
        const float eA = __expf(plA + gb);
        const float eB = __expf(plB + gb);
        se += eA + eB;
        s0 += p0A * eA + p0B * eB;
        s1 += p1A * eA + p1B * eB;
    }
    // tail: single row-quad
    for (; r < sz; r += 4) {
        const float* row = states + (size_t)(off + r) * D_FEAT_K;
        float pl = 0.f, p0 = 0.f, p1 = 0.f;
#pragma unroll
        for (int k = 0; k < 4; ++k) {
            floatx4 s = __builtin_nontemporal_load(
                reinterpret_cast<const floatx4*>(row + 4 * q + 64 * k));
            pl += s.x * gw[k].x  + s.y * gw[k].y  + s.z * gw[k].z  + s.w * gw[k].w;
            p0 += s.x * owA[k].x + s.y * owA[k].z + s.z * owB[k].x + s.w * owB[k].z;
            p1 += s.x * owA[k].y + s.y * owA[k].w + s.z * owB[k].y + s.w * owB[k].w;
        }
#pragma unroll
        for (int m = 8; m >= 1; m >>= 1) pl += __shfl_xor(pl, m);
        const float e = __expf(pl + gb);
        se += e;
        s0 += p0 * e;
        s1 += p1 * e;
    }

    // single final reduction across all 64 lanes
#pragma unroll
    for (int m = 32; m >= 1; m >>= 1) {
        se += __shfl_xor(se, m);
        s0 += __shfl_xor(s0, m);
        s1 += __shfl_xor(s1, m);
    }
    if (lane == 0) {
        const float S   = se * 0.0625f;          // undo exact 16x overcount
        const float inv = 1.0f / (S + 1e-16f);
        outp[g] = make_float2((s0 + out_b[0] * S) * inv,
                              (s1 + out_b[1] * S) * inv);
    }
}

extern "C" void kernel_launch(void* const* d_in, const int* in_sizes, int n_in,
                              void* d_out, int out_size, void* d_ws, size_t ws_size,
                              hipStream_t stream) {
    const float* states      = (const float*)d_in[0];
    const int*   graph_sizes = (const int*)d_in[1];
    const float* gate_w      = (const float*)d_in[2];
    const float* gate_b      = (const float*)d_in[3];
    const float* out_w       = (const float*)d_in[4];
    const float* out_b       = (const float*)d_in[5];

    const int n_graphs = in_sizes[1];              // 10000

    fused_kernel<<<(n_graphs + 3) / 4, 256, 0, stream>>>(
        states, graph_sizes, gate_w, gate_b, out_w, out_b,
        (float2*)d_out, n_graphs);
}

// Round 7
// 89.438 us; speedup vs baseline: 1.0549x; 1.0549x over previous
//
#include <hip/hip_runtime.h>
#include <hip/hip_bf16.h>

#define D_FEAT_K 256

typedef float floatx4 __attribute__((ext_vector_type(4)));

// --- fully fused, single dispatch --------------------------------------
// result[g,c] = (sum_i o_i,c*e_i + b_c*S) / (S + 1e-16), e_i = exp(l_i)
// (global-max subtraction cancels algebraically; eps-term shift ~1e-14)
//
// Work decomposition: each 256-thread block handles TWO graphs; each graph
// is split across TWO waves (rows striped mod 8) to halve the work-unit
// size -> smoother end-of-kernel drain. Wave partials are combined via
// 48 B of LDS + one __syncthreads().
// Within a wave: 16 lanes per row, 4 row-stripes; only the gate logit is
// reduced per row (butterfly leaves sum in all 16 lanes), o-projection
// partials accumulate per-lane and are reduced once at the end.
__global__ __launch_bounds__(256)
void fused_kernel(const float* __restrict__ states,
                  const int* __restrict__ sizes,
                  const float* __restrict__ gate_w,
                  const float* __restrict__ gate_b,
                  const float* __restrict__ out_w,
                  const float* __restrict__ out_b,
                  float2* __restrict__ outp,
                  int n_graphs) {
    __shared__ float ls[4][3];

    const int wid  = threadIdx.x >> 6;   // 0..3
    const int lane = threadIdx.x & 63;
    const int pair = wid >> 1;           // which of 2 graphs in this block
    const int half = wid & 1;            // which half of the graph's rows
    const int g = blockIdx.x * 2 + pair;
    const bool valid = (g < n_graphs);

    // --- self-scan: off = sum(sizes[0..g)), redundant per wave -----------
    // (sizes is 40 KB -> L1/L2-resident; overlaps other waves' streaming)
    int acc = 0;
    if (valid) {
        const int nv = g >> 2;
        const int4* s4 = reinterpret_cast<const int4*>(sizes);
        for (int j = lane; j < nv; j += 64) {
            int4 v = s4[j];
            acc += v.x + v.y + v.z + v.w;
        }
        for (int j = (nv << 2) + lane; j < g; j += 64) acc += sizes[j];
    }
#pragma unroll
    for (int m = 32; m >= 1; m >>= 1) acc += __shfl_xor(acc, m);
    const int off = acc;
    const int sz  = valid ? sizes[g] : 0;

    const int q    = lane & 15;               // lane within row
    const int grp8 = (lane >> 4) + 4 * half;  // row stripe 0..7

    // per-lane weight slices: features f = 4q + 64k + j, k=0..3, j=0..3
    float4 gw[4], owA[4], owB[4];
#pragma unroll
    for (int k = 0; k < 4; ++k) {
        const int f0 = 4 * q + 64 * k;
        gw[k]  = *reinterpret_cast<const float4*>(gate_w + f0);
        // out_w is [256][2] row-major: (f,c) at 2f+c
        owA[k] = *reinterpret_cast<const float4*>(out_w + 2 * f0);       // c0(f),c1(f),c0(f+1),c1(f+1)
        owB[k] = *reinterpret_cast<const float4*>(out_w + 2 * f0 + 4);   // c0(f+2),c1(f+2),c0(f+3),c1(f+3)
    }
    const float gb = gate_b[0];

    float se = 0.f, s0 = 0.f, s1 = 0.f;   // per-lane accumulators
    for (int r = grp8; r < sz; r += 8) {
        const float* row = states + (size_t)(off + r) * D_FEAT_K;
        float pl = 0.f, p0 = 0.f, p1 = 0.f;
#pragma unroll
        for (int k = 0; k < 4; ++k) {
            floatx4 s = __builtin_nontemporal_load(
                reinterpret_cast<const floatx4*>(row + 4 * q + 64 * k));
            pl += s.x * gw[k].x  + s.y * gw[k].y  + s.z * gw[k].z  + s.w * gw[k].w;
            p0 += s.x * owA[k].x + s.y * owA[k].z + s.z * owB[k].x + s.w * owB[k].z;
            p1 += s.x * owA[k].y + s.y * owA[k].w + s.z * owB[k].y + s.w * owB[k].w;
        }
        // reduce gate logit across the 16 lanes of this row; butterfly
        // leaves the full sum in every lane of the group
#pragma unroll
        for (int m = 8; m >= 1; m >>= 1) pl += __shfl_xor(pl, m);
        const float e = __expf(pl + gb);  // redundantly in all 16 lanes
        se += e;                          // identical within group -> 16x, fixed below
        s0 += p0 * e;                     // per-lane partial of sum_i o0_i*e_i
        s1 += p1 * e;
    }
    // wave-level reduction (leaves totals in every lane)
#pragma unroll
    for (int m = 32; m >= 1; m >>= 1) {
        se += __shfl_xor(se, m);
        s0 += __shfl_xor(s0, m);
        s1 += __shfl_xor(s1, m);
    }
    if (lane == 0) {
        ls[wid][0] = se;
        ls[wid][1] = s0;
        ls[wid][2] = s1;
    }
    __syncthreads();
    if (half == 0 && lane == 0 && valid) {
        const float seT = ls[wid][0] + ls[wid + 1][0];
        const float s0T = ls[wid][1] + ls[wid + 1][1];
        const float s1T = ls[wid][2] + ls[wid + 1][2];
        const float S   = seT * 0.0625f;          // undo exact 16x overcount
        const float inv = 1.0f / (S + 1e-16f);
        outp[g] = make_float2((s0T + out_b[0] * S) * inv,
                              (s1T + out_b[1] * S) * inv);
    }
}

extern "C" void kernel_launch(void* const* d_in, const int* in_sizes, int n_in,
                              void* d_out, int out_size, void* d_ws, size_t ws_size,
                              hipStream_t stream) {
    const float* states      = (const float*)d_in[0];
    const int*   graph_sizes = (const int*)d_in[1];
    const float* gate_w      = (const float*)d_in[2];
    const float* gate_b      = (const float*)d_in[3];
    const float* out_w       = (const float*)d_in[4];
    const float* out_b       = (const float*)d_in[5];

    const int n_graphs = in_sizes[1];              // 10000

    fused_kernel<<<(n_graphs + 1) / 2, 256, 0, stream>>>(
        states, graph_sizes, gate_w, gate_b, out_w, out_b,
        (float2*)d_out, n_graphs);
}